// Round 13
// baseline (30.686 us; speedup 1.0000x reference)
//
#include <hip/hip_runtime.h>
#include <hip/hip_bf16.h>
#include <math.h>

typedef __attribute__((ext_vector_type(8))) short bf16x8;
typedef __attribute__((ext_vector_type(4))) float f32x4;

#define T_TOT 16384
#define E_ 256
#define FF_ 1024
#define NQ 10
#define TB 64            // tokens per block
#define CH 64            // f per chunk
#define NCHUNK (FF_ / CH)
#define HGRAN (TB * CH)  // shorts per hs buffer (4096 = 8 KiB)

// paired f32->bf16 RNE via v_cvt_pk_bf16_f32
__device__ __forceinline__ unsigned pkbf(float a, float b) {
    __hip_bfloat162 t = __float22bfloat162_rn(make_float2(a, b));
    return *(unsigned*)&t;
}

// ---------------------------------------------------------------------------
// Prep (coalesced): bf16 MFMA B-fragments for w2 and w1^T.  (unchanged)
// ---------------------------------------------------------------------------
__global__ __launch_bounds__(256) void ffq_prep(
    const float* __restrict__ w2, const float* __restrict__ w1,
    uint4* __restrict__ w2f, uint4* __restrict__ w1f)
{
    int id = blockIdx.x * 256 + threadIdx.x;
    if (id < 32768) {
        int n  = id >> 7;
        int k0 = (id & 127) * 8;
        const float4* s = (const float4*)(w2 + (size_t)n * FF_ + k0);
        float4 a = s[0], b = s[1];
        uint4 v;
        v.x = pkbf(a.x, a.y);
        v.y = pkbf(a.z, a.w);
        v.z = pkbf(b.x, b.y);
        v.w = pkbf(b.z, b.w);
        int idx = ((k0 >> 5) * 16 + (n >> 4)) * 64 + ((k0 >> 3) & 3) * 16 + (n & 15);
        w2f[idx] = v;
    } else if (id < 32768 + 4096) {
        int id2 = id - 32768;
        int l = id2 & 63, nt = id2 >> 6;
        int n = nt * 16 + (l & 15);
        int g = l >> 4;
        float o[8];
#pragma unroll
        for (int j = 0; j < 8; ++j) {
            int k = g * 8 + j;
            o[j] = (k < NQ) ? w1[n * NQ + k] : 0.f;
        }
        uint4 v;
        v.x = pkbf(o[0], o[1]);
        v.y = pkbf(o[2], o[3]);
        v.z = pkbf(o[4], o[5]);
        v.w = pkbf(o[6], o[7]);
        w1f[id2] = v;
    }
}

// ---------------------------------------------------------------------------
// Fused kernel v13 (occupancy-first):
//  - block = 256 thr = 4 waves; block tile 64 tok x 64 cols; wave = 64tok x
//    16 cols (acc[4], 16 VGPR). Grid = 256 tok-tiles x 4 col-quarters = 1024.
//  - LDS 20 KiB, __launch_bounds__(256,8) -> <=64 VGPR -> 8 blocks/CU =
//    32 waves/CU (2x every previous round). 8 independent blocks per CU
//    drift in phase -> barriers no longer idle the CU.
//  - CH=64 (2 kk/chunk), hs double-buffered; h-phase: wave wv owns f-tile
//    cc*4+wv for all 4 token-tiles; bias via MFMA C-operand.
//  - B depth-1 register prefetch; setprio around out-MFMA cluster.
// ---------------------------------------------------------------------------
__global__ __launch_bounds__(256, 8) void ffq_mfma(
    const float* __restrict__ x, const float* __restrict__ theta,
    const float* __restrict__ b1, const float* __restrict__ b2,
    const bf16x8* __restrict__ w1f, const bf16x8* __restrict__ w2f,
    float* __restrict__ out)
{
    __shared__ unsigned short q_s[4 * 64 * 8];      // 4 KiB
    __shared__ unsigned short hs[2 * HGRAN];        // 16 KiB (double buffer)

    const int tid = threadIdx.x;
    const int l   = tid & 63;
    const int wv  = tid >> 6;            // 0..3
    const int lr  = l & 15;
    const int g   = l >> 4;              // 0..3
    const int tb  = (blockIdx.x >> 2) * TB;
    const int nc  = (blockIdx.x & 3) * 4 + wv;   // global col-tile 0..15

    // ---- Phase 0: threads 0..63 compute q, write B-frag granules ----
    if (tid < TB) {
        const int t = tb + tid;
        float xv[NQ];
        {
            float4 a = *(const float4*)(x + (size_t)t * E_);
            float4 b = *(const float4*)(x + (size_t)t * E_ + 4);
            float2 c = *(const float2*)(x + (size_t)t * E_ + 8);
            xv[0]=a.x; xv[1]=a.y; xv[2]=a.z; xv[3]=a.w;
            xv[4]=b.x; xv[5]=b.y; xv[6]=b.z; xv[7]=b.w;
            xv[8]=c.x; xv[9]=c.y;
        }
        float mm[NQ];
#pragma unroll
        for (int w = 0; w < NQ; ++w) mm[w] = cosf(theta[w]) * cosf(xv[w]);
        float qv[NQ];
        {
            float p = mm[0];
#pragma unroll
            for (int w = 1; w < NQ; ++w) { p *= mm[w]; qv[w] = p; }
            float p0 = mm[1];
#pragma unroll
            for (int w = 2; w < NQ; ++w) p0 *= mm[w];
            qv[0] = p0;
        }
        uint4 s0, s1;
        s0.x = pkbf(qv[0], qv[1]);
        s0.y = pkbf(qv[2], qv[3]);
        s0.z = pkbf(qv[4], qv[5]);
        s0.w = pkbf(qv[6], qv[7]);
        s1.x = pkbf(qv[8], qv[9]);
        s1.y = 0; s1.z = 0; s1.w = 0;
        int tt = tid >> 4, r = tid & 15;
        uint4* base = (uint4*)q_s + tt * 64;
        base[r]      = s0;
        base[16 + r] = s1;
        base[32 + r] = make_uint4(0, 0, 0, 0);
        base[48 + r] = make_uint4(0, 0, 0, 0);
    }
    __syncthreads();

    f32x4 acc[4];
#pragma unroll
    for (int tt = 0; tt < 4; ++tt) acc[tt] = (f32x4){0.f, 0.f, 0.f, 0.f};

    // ---- h-phase: wave wv computes f-tile (cc*4+wv) for all 4 tok-tiles ----
    // D[row=f(g*4+r)][col=t(lr)]; bias as C-operand; store uint2 into the
    // A-frag granule layout of the 64x64 chunk buffer (tt-stride 2).
#define H_PHASE(cc, hdst, WF, BBC)                                             \
    {                                                                          \
        bf16x8 qfr[4];                                                         \
        _Pragma("unroll")                                                      \
        for (int tt = 0; tt < 4; ++tt)                                         \
            qfr[tt] = ((const bf16x8*)q_s)[tt * 64 + l];                       \
        const int fl   = wv * 16 + g * 4;         /* f local in chunk */       \
        const int gb   = fl >> 5;                 /* kk_local of write */      \
        const int sl   = (fl & 31) >> 3;                                       \
        const int sub  = (fl & 7) * 2;                                         \
        _Pragma("unroll")                                                      \
        for (int tt = 0; tt < 4; ++tt) {                                       \
            f32x4 d = __builtin_amdgcn_mfma_f32_16x16x32_bf16(                 \
                    (WF), qfr[tt], (BBC), 0, 0, 0);                            \
            unsigned p0 = pkbf(fmaxf(d[0], 0.f), fmaxf(d[1], 0.f));            \
            unsigned p1 = pkbf(fmaxf(d[2], 0.f), fmaxf(d[3], 0.f));            \
            unsigned byteoff = (unsigned)((tt * 2 + gb) * 64 + lr + 16 * sl)   \
                               * 16u + (unsigned)sub;                          \
            *(uint2*)((char*)(hdst) + byteoff) = make_uint2(p0, p1);           \
        }                                                                      \
    }

    // ---- one out-step (kk_local J): A in-step, B depth-1 prefetch ----
#define OUT_STEP(J)                                                            \
    {                                                                          \
        const int kk  = c * 2 + (J);                                           \
        const int kkn = (kk + 1 < 32) ? kk + 1 : 31;                           \
        bf16x8 bn = w2f[(kkn * 16 + nc) * 64 + l];                             \
        bf16x8 af[4];                                                          \
        _Pragma("unroll")                                                      \
        for (int tt = 0; tt < 4; ++tt)                                         \
            af[tt] = hc[(tt * 2 + (J)) * 64 + l];                              \
        _Pragma("unroll")                                                      \
        for (int tt = 0; tt < 4; ++tt)                                         \
            acc[tt] = __builtin_amdgcn_mfma_f32_16x16x32_bf16(                 \
                af[tt], bc, acc[tt], 0, 0, 0);                                 \
        bc = bn;                                                               \
    }

    // ---- prologue: chunk 0 h-phase into buf0; init B prefetch ----
    {
        bf16x8 wf0 = w1f[(0 * 4 + wv) * 64 + l];
        f32x4  bb0 = *(const f32x4*)(b1 + (0 * 4 + wv) * 16 + g * 4);
        H_PHASE(0, hs, wf0, bb0)
    }
    bf16x8 bc = w2f[(0 * 16 + nc) * 64 + l];
    __syncthreads();

    for (int c = 0; c < NCHUNK; ++c) {
        const bf16x8*   hc = (const bf16x8*)(hs + (c & 1) * HGRAN);
        unsigned short* hn = hs + ((c & 1) ^ 1) * HGRAN;

        // issue next chunk's h-inputs early (land during MFMA cluster)
        bf16x8 wfc; f32x4 bbc;
        if (c < NCHUNK - 1) {
            wfc = w1f[((c + 1) * 4 + wv) * 64 + l];
            bbc = *(const f32x4*)(b1 + ((c + 1) * 4 + wv) * 16 + g * 4);
        }

        __builtin_amdgcn_s_setprio(1);
        OUT_STEP(0)
        OUT_STEP(1)
        __builtin_amdgcn_s_setprio(0);

        if (c < NCHUNK - 1) {
            H_PHASE(c + 1, hn, wfc, bbc)
        }
        __syncthreads();
    }
#undef OUT_STEP
#undef H_PHASE

    // ---- epilogue: + b2, store fp32 (no split-K) ----
    {
        const int col = nc * 16 + lr;
        const float bbv = b2[col];
#pragma unroll
        for (int tt = 0; tt < 4; ++tt) {
#pragma unroll
            for (int r = 0; r < 4; ++r) {
                int tr = tb + tt * 16 + g * 4 + r;
                out[(size_t)tr * E_ + col] = acc[tt][r] + bbv;
            }
        }
    }
}

extern "C" void kernel_launch(void* const* d_in, const int* in_sizes, int n_in,
                              void* d_out, int out_size, void* d_ws, size_t ws_size,
                              hipStream_t stream) {
    const float* x     = (const float*)d_in[0];
    const float* theta = (const float*)d_in[1];
    const float* w1    = (const float*)d_in[2];
    const float* b1    = (const float*)d_in[3];
    const float* w2    = (const float*)d_in[4];
    const float* b2    = (const float*)d_in[5];
    float* out = (float*)d_out;

    uint4* w2f = (uint4*)d_ws;                          // 512 KiB
    uint4* w1f = (uint4*)((char*)d_ws + 512 * 1024);    // 64 KiB

    hipLaunchKernelGGL(ffq_prep, dim3(144), dim3(256), 0, stream,
                       w2, w1, w2f, w1f);
    hipLaunchKernelGGL(ffq_mfma, dim3(4 * T_TOT / TB), dim3(256), 0, stream,
                       x, theta, b1, b2,
                       (const bf16x8*)w1f, (const bf16x8*)w2f, out);
}

// Round 14
// 27.646 us; speedup vs baseline: 1.1099x; 1.1099x over previous
//
#include <hip/hip_runtime.h>
#include <hip/hip_bf16.h>
#include <math.h>

typedef __attribute__((ext_vector_type(8))) short bf16x8;
typedef __attribute__((ext_vector_type(4))) float f32x4;

#define T_TOT 16384
#define E_ 256
#define FF_ 1024
#define NQ 10
#define TB 64
#define CH 128                  // f per chunk (8 f-tiles)
#define NCHUNK (FF_ / CH)       // 8
#define HGRAN (TB * CH)         // 8192 shorts = 16 KiB per hs buffer
#define BPAIR (32 * 512)        // shorts per B pair-buffer (32 granules x 1 KiB)

// paired f32->bf16 RNE via v_cvt_pk_bf16_f32
__device__ __forceinline__ unsigned pkbf(float a, float b) {
    __hip_bfloat162 t = __float22bfloat162_rn(make_float2(a, b));
    return *(unsigned*)&t;
}

// ---------------------------------------------------------------------------
// Prep (coalesced): bf16 MFMA B-fragments for w2 and w1^T.  (unchanged)
// ---------------------------------------------------------------------------
__global__ __launch_bounds__(256) void ffq_prep(
    const float* __restrict__ w2, const float* __restrict__ w1,
    uint4* __restrict__ w2f, uint4* __restrict__ w1f)
{
    int id = blockIdx.x * 256 + threadIdx.x;
    if (id < 32768) {
        int n  = id >> 7;
        int k0 = (id & 127) * 8;
        const float4* s = (const float4*)(w2 + (size_t)n * FF_ + k0);
        float4 a = s[0], b = s[1];
        uint4 v;
        v.x = pkbf(a.x, a.y);
        v.y = pkbf(a.z, a.w);
        v.z = pkbf(b.x, b.y);
        v.w = pkbf(b.z, b.w);
        int idx = ((k0 >> 5) * 16 + (n >> 4)) * 64 + ((k0 >> 3) & 3) * 16 + (n & 15);
        w2f[idx] = v;
    } else if (id < 32768 + 4096) {
        int id2 = id - 32768;
        int l = id2 & 63, nt = id2 >> 6;
        int n = nt * 16 + (l & 15);
        int g = l >> 4;
        float o[8];
#pragma unroll
        for (int j = 0; j < 8; ++j) {
            int k = g * 8 + j;
            o[j] = (k < NQ) ? w1[n * NQ + k] : 0.f;
        }
        uint4 v;
        v.x = pkbf(o[0], o[1]);
        v.y = pkbf(o[2], o[3]);
        v.z = pkbf(o[4], o[5]);
        v.w = pkbf(o[6], o[7]);
        w1f[id2] = v;
    }
}

// ---------------------------------------------------------------------------
// Fused kernel v14 (m97-pattern):
//  - grid 256: block = 64 tok x 256 cols (FULL width -> B shared block-wide,
//    zero redundancy). 8 waves; wave = 4 token-tiles x 2 col-tiles, acc[4][2].
//  - B staged into LDS in kk-PAIRS (32 KiB, double-buffered): loads issued at
//    pair start (T14 issue-early), ds_write just before the barrier. Out-phase
//    reads B via conflict-free ds_read_b128 instead of per-step L2 loads.
//  - h-phase every 2 pairs into double-buffered hs (verified CH=128 layout).
//  - 1 barrier per pair; LDS 100 KiB -> 1 block/CU.
// ---------------------------------------------------------------------------
__global__ __launch_bounds__(512, 2) void ffq_mfma(
    const float* __restrict__ x, const float* __restrict__ theta,
    const float* __restrict__ b1, const float* __restrict__ b2,
    const bf16x8* __restrict__ w1f, const bf16x8* __restrict__ w2f,
    float* __restrict__ out)
{
    __shared__ unsigned short q_s[4 * 64 * 8];   // 4 KiB
    __shared__ unsigned short hs[2 * HGRAN];     // 32 KiB (double buffer)
    __shared__ unsigned short Bl[2 * BPAIR];     // 64 KiB (double buffer)

    const int tid = threadIdx.x;
    const int l   = tid & 63;
    const int wv  = tid >> 6;        // 0..7
    const int lr  = l & 15;
    const int g   = l >> 4;          // 0..3
    const int tb  = blockIdx.x * TB;
    const int nc0 = wv * 2;          // wave's col-tiles
    const int nc1 = wv * 2 + 1;

    // ---- Phase 0: threads 0..63 compute q, write B-frag granules ----
    if (tid < TB) {
        const int t = tb + tid;
        float xv[NQ];
        {
            float4 a = *(const float4*)(x + (size_t)t * E_);
            float4 b = *(const float4*)(x + (size_t)t * E_ + 4);
            float2 c = *(const float2*)(x + (size_t)t * E_ + 8);
            xv[0]=a.x; xv[1]=a.y; xv[2]=a.z; xv[3]=a.w;
            xv[4]=b.x; xv[5]=b.y; xv[6]=b.z; xv[7]=b.w;
            xv[8]=c.x; xv[9]=c.y;
        }
        float mm[NQ];
#pragma unroll
        for (int w = 0; w < NQ; ++w) mm[w] = cosf(theta[w]) * cosf(xv[w]);
        float qv[NQ];
        {
            float p = mm[0];
#pragma unroll
            for (int w = 1; w < NQ; ++w) { p *= mm[w]; qv[w] = p; }
            float p0 = mm[1];
#pragma unroll
            for (int w = 2; w < NQ; ++w) p0 *= mm[w];
            qv[0] = p0;
        }
        uint4 s0, s1;
        s0.x = pkbf(qv[0], qv[1]);
        s0.y = pkbf(qv[2], qv[3]);
        s0.z = pkbf(qv[4], qv[5]);
        s0.w = pkbf(qv[6], qv[7]);
        s1.x = pkbf(qv[8], qv[9]);
        s1.y = 0; s1.z = 0; s1.w = 0;
        int tt = tid >> 4, r = tid & 15;
        uint4* base = (uint4*)q_s + tt * 64;
        base[r]      = s0;
        base[16 + r] = s1;
        base[32 + r] = make_uint4(0, 0, 0, 0);
        base[48 + r] = make_uint4(0, 0, 0, 0);
    }

    f32x4 acc[4][2];
#pragma unroll
    for (int tt = 0; tt < 4; ++tt)
#pragma unroll
        for (int nn = 0; nn < 2; ++nn) acc[tt][nn] = (f32x4){0.f,0.f,0.f,0.f};

    // ---- h-phase: wave wv computes global f-tile (cc*8 + wv), 4 tok-tiles ----
#define H_PHASE(cc, hdst)                                                      \
    {                                                                          \
        const int ntg = (cc) * 8 + wv;                                         \
        bf16x8 wf  = w1f[ntg * 64 + l];                                        \
        f32x4  bbc = *(const f32x4*)(b1 + ntg * 16 + g * 4);                   \
        bf16x8 qfr[4];                                                         \
        _Pragma("unroll")                                                      \
        for (int tt = 0; tt < 4; ++tt)                                         \
            qfr[tt] = ((const bf16x8*)q_s)[tt * 64 + l];                       \
        const int fl  = wv * 16 + g * 4;        /* f local in chunk */         \
        const int kkl = fl >> 5;                                               \
        const int sl  = (fl & 31) >> 3;                                        \
        const int sub = (fl & 7) * 2;                                          \
        _Pragma("unroll")                                                      \
        for (int tt = 0; tt < 4; ++tt) {                                       \
            f32x4 d = __builtin_amdgcn_mfma_f32_16x16x32_bf16(                 \
                    wf, qfr[tt], bbc, 0, 0, 0);                                \
            unsigned p0 = pkbf(fmaxf(d[0], 0.f), fmaxf(d[1], 0.f));            \
            unsigned p1 = pkbf(fmaxf(d[2], 0.f), fmaxf(d[3], 0.f));            \
            unsigned byteoff = (unsigned)((tt * 4 + kkl) * 64 + lr + 16 * sl)  \
                               * 16u + (unsigned)sub;                          \
            *(uint2*)((char*)(hdst) + byteoff) = make_uint2(p0, p1);           \
        }                                                                      \
    }

    // ---- prologue: load pair 0 to regs, write to Bl[0]; q; barrier ----
    bf16x8 stg[4];
#pragma unroll
    for (int r = 0; r < 4; ++r)
        stg[r] = w2f[(0 * 32 + r * 8 + wv) * 64 + l];
#pragma unroll
    for (int r = 0; r < 4; ++r)
        ((bf16x8*)Bl)[(r * 8 + wv) * 64 + l] = stg[r];
    __syncthreads();

    H_PHASE(0, hs)
    // issue pair-1 loads early (land during barrier + first pair compute)
#pragma unroll
    for (int r = 0; r < 4; ++r)
        stg[r] = w2f[(1 * 32 + r * 8 + wv) * 64 + l];
    __syncthreads();

#pragma unroll 2
    for (int p = 0; p < 16; ++p) {
        const bf16x8* bcur = (const bf16x8*)(Bl + (p & 1) * BPAIR);
        bf16x8*       bnxt = (bf16x8*)(Bl + ((p & 1) ^ 1) * BPAIR);
        const bf16x8* hc   = (const bf16x8*)(hs + ((p >> 1) & 1) * HGRAN);

        // ---- compute the pair's two kk-steps from LDS ----
#pragma unroll
        for (int e = 0; e < 2; ++e) {
            const int kkl = ((p & 1) << 1) + e;      // kk & 3
            bf16x8 af[4];
#pragma unroll
            for (int tt = 0; tt < 4; ++tt)
                af[tt] = hc[(tt * 4 + kkl) * 64 + l];
            bf16x8 b0 = bcur[(e * 16 + nc0) * 64 + l];
            bf16x8 b1v = bcur[(e * 16 + nc1) * 64 + l];
#pragma unroll
            for (int tt = 0; tt < 4; ++tt)
                acc[tt][0] = __builtin_amdgcn_mfma_f32_16x16x32_bf16(
                    af[tt], b0, acc[tt][0], 0, 0, 0);
#pragma unroll
            for (int tt = 0; tt < 4; ++tt)
                acc[tt][1] = __builtin_amdgcn_mfma_f32_16x16x32_bf16(
                    af[tt], b1v, acc[tt][1], 0, 0, 0);
        }

        // ---- h-phase for the next chunk at end of each odd pair ----
        if ((p & 1) == 1 && p < 15) {
            H_PHASE((p >> 1) + 1, hs + (((p >> 1) & 1) ^ 1) * HGRAN)
        }

        // ---- write staged pair p+1 into LDS; issue loads for pair p+2 ----
        if (p < 15) {
#pragma unroll
            for (int r = 0; r < 4; ++r)
                bnxt[(r * 8 + wv) * 64 + l] = stg[r];
            if (p < 14) {
#pragma unroll
                for (int r = 0; r < 4; ++r)
                    stg[r] = w2f[((p + 2) * 32 + r * 8 + wv) * 64 + l];
            }
        }
        __syncthreads();
    }
#undef H_PHASE

    // ---- epilogue: + b2, store fp32 ----
    {
        const int col0 = nc0 * 16 + lr;
        const int col1 = col0 + 16;
        const float bb0 = b2[col0];
        const float bb1 = b2[col1];
#pragma unroll
        for (int tt = 0; tt < 4; ++tt) {
#pragma unroll
            for (int r = 0; r < 4; ++r) {
                int tr = tb + tt * 16 + g * 4 + r;
                out[(size_t)tr * E_ + col0] = acc[tt][0][r] + bb0;
                out[(size_t)tr * E_ + col1] = acc[tt][1][r] + bb1;
            }
        }
    }
}

extern "C" void kernel_launch(void* const* d_in, const int* in_sizes, int n_in,
                              void* d_out, int out_size, void* d_ws, size_t ws_size,
                              hipStream_t stream) {
    const float* x     = (const float*)d_in[0];
    const float* theta = (const float*)d_in[1];
    const float* w1    = (const float*)d_in[2];
    const float* b1    = (const float*)d_in[3];
    const float* w2    = (const float*)d_in[4];
    const float* b2    = (const float*)d_in[5];
    float* out = (float*)d_out;

    uint4* w2f = (uint4*)d_ws;                          // 512 KiB
    uint4* w1f = (uint4*)((char*)d_ws + 512 * 1024);    // 64 KiB

    hipLaunchKernelGGL(ffq_prep, dim3(144), dim3(256), 0, stream,
                       w2, w1, w2f, w1f);
    hipLaunchKernelGGL(ffq_mfma, dim3(T_TOT / TB), dim3(512), 0, stream,
                       x, theta, b1, b2,
                       (const bf16x8*)w1f, (const bf16x8*)w2f, out);
}